// Round 7
// baseline (83568.732 us; speedup 1.0000x reference)
//
#include <hip/hip_runtime.h>
#include <hip/hip_bf16.h>

// Problem constants
#define SEQ  256
#define BSZ  128
#define DM   512
#define HID  1536
#define KTOT 2560      // x(512) | r(512) | h(1536)
#define VC   6144      // virtual cols: [0,3072) fused rz, [3072,4608) inn, [4608,6144) hn
#define NBLK 512       // 2 blocks/CU exactly -> co-resident by capacity

typedef __attribute__((ext_vector_type(4))) float f32x4;
typedef __attribute__((ext_vector_type(8))) short short8;
typedef __attribute__((ext_vector_type(4))) unsigned short us4;
typedef __attribute__((ext_vector_type(4))) unsigned int u32x4;

// ws layout (bytes)
#define OFF_WBH 0ull                 // bf16 [4608][2560] hi   = 23,592,960
#define OFF_WBL 23592960ull          // bf16 [4608][2560] lo   = 23,592,960
#define OFF_P   47185920ull          // f32  [8 xcd][5 ks][16 b][6144] = 15,728,640
#define OFF_R32 62914560ull          // f32  [128][512]        =    262,144
#define OFF_A   63176704ull          // f32  [1024][64][64]    = 16,777,216   (zeroed)
#define OFF_H32 79953920ull          // f32  [128][1536]       =    786,432   (zeroed)
#define OFF_RBH 80740352ull          // bf16 [128][512]  hi    (zeroed)
#define OFF_RBL 80871424ull          // bf16 [128][512]  lo    (zeroed)
#define OFF_HBH 81002496ull          // bf16 [128][1536] hi    (zeroed)
#define OFF_HBL 81395712ull          // bf16 [128][1536] lo    (zeroed)
#define OFF_BAR 81788928ull          // 1024 uints: cntX[x*32] @0..255, barX[256+x*32+{0,1}], rendezvous @512,513
// pk_zero region: OFF_A..OFF_BAR = 18,612,224 B = 1,163,264 x 16B = 4544 blocks x 256

static __device__ __forceinline__ unsigned short bf(float x) {
  __hip_bfloat16 h = __float2bfloat16(x);
  return *reinterpret_cast<unsigned short*>(&h);
}
static __device__ __forceinline__ float bf2f(unsigned short u) {
  union { unsigned int i; float f; } c; c.i = ((unsigned int)u) << 16;
  return c.f;
}
static __device__ __forceinline__ float ldf_sc0(const float* p) {   // L1-bypass, L2-served
  return __hip_atomic_load(p, __ATOMIC_RELAXED, __HIP_MEMORY_SCOPE_AGENT);
}
static __device__ __forceinline__ short8 ntl(const unsigned short* p) {  // streaming W read
  return __builtin_nontemporal_load((const short8*)p);
}
// 4x 16B sc0 loads + single drain (L1-bypass; data written by same-XCD blocks)
static __device__ __forceinline__ void ld4_sc0(
    const unsigned short* p0, const unsigned short* p1,
    const unsigned short* p2, const unsigned short* p3,
    u32x4& r0, u32x4& r1, u32x4& r2, u32x4& r3) {
  asm volatile(
      "global_load_dwordx4 %0, %4, off sc0\n\t"
      "global_load_dwordx4 %1, %5, off sc0\n\t"
      "global_load_dwordx4 %2, %6, off sc0\n\t"
      "global_load_dwordx4 %3, %7, off sc0\n\t"
      "s_waitcnt vmcnt(0)"
      : "=&v"(r0), "=&v"(r1), "=&v"(r2), "=&v"(r3)
      : "v"(p0), "v"(p1), "v"(p2), "v"(p3)
      : "memory");
}

// ---- barrier over n blocks: RMW arrive at LLC + SYSTEM-scope poll. NO cache fences.
// __syncthreads() drains vmcnt(0) (compiler-emitted) so all waves' stores are in L2
// before tid0 arrives; same-XCD consumers read via sc0 -> L2 -> always fresh.
static __device__ __forceinline__ void barrier_n(unsigned* b, unsigned n) {
  __syncthreads();
  if (threadIdx.x == 0) {
    unsigned e = __hip_atomic_load(b + 1, __ATOMIC_RELAXED, __HIP_MEMORY_SCOPE_SYSTEM);
    if (atomicAdd(b, 1u) == n - 1u) {
      atomicSub(b, n);
      atomicAdd(b + 1, 1u);
    } else {
      while (__hip_atomic_load(b + 1, __ATOMIC_RELAXED, __HIP_MEMORY_SCOPE_SYSTEM) == e)
        __builtin_amdgcn_s_sleep(8);
    }
  }
  __syncthreads();
}

// ---------------- prep: repack weights to hi/lo bf16 [4608][2560]; zero barrier ----------------
__global__ __launch_bounds__(256) void pk_wb(const float* __restrict__ Wih,
                                             const float* __restrict__ Whh,
                                             unsigned short* __restrict__ Wh,
                                             unsigned short* __restrict__ Wl,
                                             unsigned* __restrict__ bar) {
  if (blockIdx.x == 0)
    for (int i = threadIdx.x; i < 1024; i += 256) bar[i] = 0u;
  int idx = blockIdx.x * 256 + threadIdx.x;        // < 4608*640 = 2,949,120
  int row = idx / 640;
  int k = (idx - row * 640) * 4;
  const float* src = (k < 1024) ? (Wih + (size_t)row * 1024 + k)
                                : (Whh + (size_t)row * HID + (k - 1024));
  f32x4 v = *(const f32x4*)src;
  us4 oh, ol;
#pragma unroll
  for (int i = 0; i < 4; ++i) {
    unsigned short h = bf(v[i]);
    oh[i] = h;
    ol[i] = bf(v[i] - bf2f(h));
  }
  *(us4*)(Wh + (size_t)row * KTOT + k) = oh;
  *(us4*)(Wl + (size_t)row * KTOT + k) = ol;
}

__global__ __launch_bounds__(256) void pk_zero(f32x4* __restrict__ dst) {
  f32x4 z = {0.f, 0.f, 0.f, 0.f};
  dst[(size_t)blockIdx.x * 256 + threadIdx.x] = z;
}

// ---------------- persistent fused kernel, XCD-local recurrence ----------------
// 512 blocks (2/CU). XCD g owns batches 16g..16g+15. Per step per XCD:
// 720 GEMM tasks [16b x 32col x 512K] (rz 96jg*5ks + inn 48jg*2ks + hn 48jg*3ks),
// then pair phase (128 pairs/XCD). Only per-XCD barriers; no fences anywhere.
__global__ __launch_bounds__(256, 2) void fused(
    const float* __restrict__ x, const float* __restrict__ bih,
    const float* __restrict__ bhh, char* __restrict__ ws,
    float* __restrict__ dout)
{
  const unsigned short* Wh = (const unsigned short*)(ws + OFF_WBH);
  const unsigned short* Wl = (const unsigned short*)(ws + OFF_WBL);
  float*          P   = (float*)(ws + OFF_P);
  float*          r32 = (float*)(ws + OFF_R32);
  float*          A   = (float*)(ws + OFF_A);
  float*          h32 = (float*)(ws + OFF_H32);
  unsigned short* Rbh = (unsigned short*)(ws + OFF_RBH);
  unsigned short* Rbl = (unsigned short*)(ws + OFF_RBL);
  unsigned short* Hbh = (unsigned short*)(ws + OFF_HBH);
  unsigned short* Hbl = (unsigned short*)(ws + OFF_HBL);
  unsigned* bar = (unsigned*)(ws + OFF_BAR);

  const int tid = threadIdx.x;
  unsigned xcd;
  asm volatile("s_getreg_b32 %0, hwreg(HW_REG_XCC_ID)" : "=s"(xcd));
  xcd &= 7;

  // ---- rendezvous: register with this XCD, then one grid-wide barrier ----
  __shared__ unsigned rankS;
  if (tid == 0) rankS = atomicAdd(&bar[xcd * 32], 1u);
  __syncthreads();
  const unsigned rank = rankS;
  barrier_n(&bar[512], NBLK);
  const unsigned cnt_g =
      __hip_atomic_load(&bar[xcd * 32], __ATOMIC_RELAXED, __HIP_MEMORY_SCOPE_SYSTEM);
  unsigned* xbar = &bar[256 + xcd * 32];

  const int wave = tid >> 6, lane = tid & 63;
  const int l15 = lane & 15, kg = lane >> 4;
  const int srow = tid >> 4;              // staging row 0..15
  const int sc0_ = (tid & 15) * 32;       // staging col base (32 shorts)

  __shared__ __align__(16) unsigned short AH[16 * 520];   // [16][512] +8 pad
  __shared__ __align__(16) unsigned short AL[16 * 520];
  __shared__ __align__(16) float kS[4][64];
  __shared__ __align__(16) float qS[4][64];

  for (int t = 0; t < SEQ; ++t) {
    // ================= GEMM phase: tasks strided over this XCD's blocks =============
    for (unsigned u = rank; u < 720u; u += cnt_g) {
      int jg, ks;
      if (u < 480u)      { jg = u / 5;                 ks = u % 5; }
      else if (u < 576u) { unsigned v = u - 480u; jg = 96  + v / 2; ks = v % 2; }
      else               { unsigned v = u - 576u; jg = 144 + v / 3; ks = 2 + v % 3; }
      const int wrow0 = (jg < 144 ? jg * 32 : jg * 32 - 1536);
      const int kc0   = ks * 512;

      __syncthreads();   // previous task's LDS readers done
      // ---- stage acts [16][512] hi/lo ----
      if (ks == 0) {            // x (f32 -> hi/lo bf16)
        const float* p = x + ((size_t)t * BSZ + xcd * 16 + srow) * DM + sc0_;
#pragma unroll
        for (int j = 0; j < 8; ++j) {
          f32x4 f = ((const f32x4*)p)[j];
          us4 hh, ll;
#pragma unroll
          for (int i = 0; i < 4; ++i) {
            unsigned short h = bf(f[i]);
            hh[i] = h; ll[i] = bf(f[i] - bf2f(h));
          }
          *(us4*)&AH[srow * 520 + sc0_ + j * 4] = hh;
          *(us4*)&AL[srow * 520 + sc0_ + j * 4] = ll;
        }
      } else {
        const unsigned short *ph, *pl;
        if (ks == 1) {          // r
          size_t off = (size_t)(xcd * 16 + srow) * DM + sc0_;
          ph = Rbh + off; pl = Rbl + off;
        } else {                // h
          size_t off = (size_t)(xcd * 16 + srow) * HID + (kc0 - 1024) + sc0_;
          ph = Hbh + off; pl = Hbl + off;
        }
        u32x4 h0, h1, h2, h3, l0, l1, l2, l3;
        ld4_sc0(ph, ph + 8, ph + 16, ph + 24, h0, h1, h2, h3);
        ld4_sc0(pl, pl + 8, pl + 16, pl + 24, l0, l1, l2, l3);
        *(u32x4*)&AH[srow * 520 + sc0_     ] = h0;
        *(u32x4*)&AH[srow * 520 + sc0_ + 8 ] = h1;
        *(u32x4*)&AH[srow * 520 + sc0_ + 16] = h2;
        *(u32x4*)&AH[srow * 520 + sc0_ + 24] = h3;
        *(u32x4*)&AL[srow * 520 + sc0_     ] = l0;
        *(u32x4*)&AL[srow * 520 + sc0_ + 8 ] = l1;
        *(u32x4*)&AL[srow * 520 + sc0_ + 16] = l2;
        *(u32x4*)&AL[srow * 520 + sc0_ + 24] = l3;
      }
      __syncthreads();

      // ---- 16 k-iters, 6 MFMA each (hi*hi, hi*lo, lo*hi), W via nt streaming ----
      f32x4 acc0 = {0.f, 0.f, 0.f, 0.f}, acc1 = {0.f, 0.f, 0.f, 0.f};
      const unsigned short* wa_h = Wh + (size_t)(wrow0 + l15) * KTOT + kc0 + kg * 8;
      const unsigned short* wb_h = wa_h + (size_t)16 * KTOT;
      const unsigned short* wa_l = Wl + (size_t)(wrow0 + l15) * KTOT + kc0 + kg * 8;
      const unsigned short* wb_l = wa_l + (size_t)16 * KTOT;
#pragma unroll
      for (int it = 0; it < 16; ++it) {
        short8 wh0 = ntl(wa_h + it * 32);
        short8 wh1 = ntl(wb_h + it * 32);
        short8 wl0 = ntl(wa_l + it * 32);
        short8 wl1 = ntl(wb_l + it * 32);
        short8 ah = *(const short8*)&AH[(size_t)l15 * 520 + it * 32 + kg * 8];
        short8 al = *(const short8*)&AL[(size_t)l15 * 520 + it * 32 + kg * 8];
        acc0 = __builtin_amdgcn_mfma_f32_16x16x32_bf16(ah, wh0, acc0, 0, 0, 0);
        acc0 = __builtin_amdgcn_mfma_f32_16x16x32_bf16(ah, wl0, acc0, 0, 0, 0);
        acc0 = __builtin_amdgcn_mfma_f32_16x16x32_bf16(al, wh0, acc0, 0, 0, 0);
        acc1 = __builtin_amdgcn_mfma_f32_16x16x32_bf16(ah, wh1, acc1, 0, 0, 0);
        acc1 = __builtin_amdgcn_mfma_f32_16x16x32_bf16(ah, wl1, acc1, 0, 0, 0);
        acc1 = __builtin_amdgcn_mfma_f32_16x16x32_bf16(al, wh1, acc1, 0, 0, 0);
      }
      // ---- write P partial (plain stores; same-XCD consumers use sc0) ----
      float* Po = P + (((size_t)xcd * 5 + ks) * 16) * VC + jg * 32;
#pragma unroll
      for (int i = 0; i < 4; ++i) {
        Po[(size_t)(kg * 4 + i) * VC + l15]      = acc0[i];
        Po[(size_t)(kg * 4 + i) * VC + 16 + l15] = acc1[i];
      }
    }
    barrier_n(xbar, cnt_g);

    // ================= pair phase: 128 pairs/XCD, strided over waves =============
    for (unsigned p = rank * 4 + wave; p < 128u; p += cnt_g * 4) {
      const int b_l = p >> 3, n = p & 7;
      const int b_g = xcd * 16 + b_l;
      const unsigned pair_g = (unsigned)b_g * 8 + n;
      const int l = lane;
      const float* Pb = P + ((size_t)xcd * 5 * 16 + b_l) * VC;
      const size_t KS = (size_t)16 * VC;     // ksi stride
      float hv[3];
#pragma unroll
      for (int s = 0; s < 3; ++s) {
        int c = s * 512 + n * 64 + l;
        float sr2 = 0.f, sz = 0.f;
#pragma unroll
        for (int ksi = 0; ksi < 5; ++ksi) {
          sr2 += ldf_sc0(Pb + ksi * KS + c);
          sz  += ldf_sc0(Pb + ksi * KS + 1536 + c);
        }
        float gin = ldf_sc0(Pb + 3072 + c) + ldf_sc0(Pb + KS + 3072 + c);
        float ghn = 0.f;
#pragma unroll
        for (int ksi = 2; ksi < 5; ++ksi) ghn += ldf_sc0(Pb + ksi * KS + 4608 + c);
        float rg = 1.f / (1.f + __expf(-(sr2 + bih[c] + bhh[c])));
        float zg = 1.f / (1.f + __expf(-(sz + bih[1536 + c] + bhh[1536 + c])));
        float nn = tanhf(gin + bih[3072 + c] + rg * (ghn + bhh[3072 + c]));
        size_t hix = (size_t)b_g * HID + c;
        float hp = h32[hix];
        float hnew = (1.f - zg) * nn + zg * hp;
        h32[hix] = hnew;
        unsigned short hh2 = bf(hnew);
        Hbh[hix] = hh2;
        Hbl[hix] = bf(hnew - bf2f(hh2));
        hv[s] = hnew;
      }
      float ssq = hv[0] * hv[0], ssk = hv[1] * hv[1];
#pragma unroll
      for (int off = 32; off > 0; off >>= 1) {
        ssq += __shfl_xor(ssq, off);
        ssk += __shfl_xor(ssk, off);
      }
      float qn = hv[0] * rsqrtf(ssq);
      float kn = hv[1] * rsqrtf(ssk);
      float ke = kn > 0.f ? kn : expm1f(kn);   // elu(unitnorm)
      kS[wave][l] = ke;
      qS[wave][l] = qn;                        // wave-local: no sync needed

      float vvl = hv[2];
      float* Arow = A + ((size_t)pair_g * 64 + l) * 64;
      float racc = 0.f;
#pragma unroll
      for (int q4 = 0; q4 < 16; ++q4) {
        f32x4 a  = *(f32x4*)(Arow + q4 * 4);
        f32x4 kk = *(f32x4*)&kS[wave][q4 * 4];
        f32x4 qq = *(f32x4*)&qS[wave][q4 * 4];
        a[0] += kk[0] * vvl; a[1] += kk[1] * vvl;
        a[2] += kk[2] * vvl; a[3] += kk[3] * vvl;
        racc += qq[0] * a[0] + qq[1] * a[1] + qq[2] * a[2] + qq[3] * a[3];
        *(f32x4*)(Arow + q4 * 4) = a;
      }
      size_t ri = (size_t)b_g * DM + n * 64 + l;
      r32[ri] = racc;
      unsigned short rh2 = bf(racc);
      Rbh[ri] = rh2;
      Rbl[ri] = bf(racc - bf2f(rh2));

      if (t == SEQ - 1) {
        dout[65536  + pair_g * 64 + l] = ke;   // k output (f32)
        dout[131072 + pair_g * 64 + l] = qn;   // q output (f32)
      }
    }
    barrier_n(xbar, cnt_g);
  }
}

// ---------------- final: out = r @ Wo.T + bo (f32) ----------------
__global__ __launch_bounds__(512) void out_gemm(const float* __restrict__ r32,
                                                const float* __restrict__ Wo,
                                                const float* __restrict__ bo,
                                                float* __restrict__ dout) {
  int b0 = blockIdx.x * 2;
  int o  = threadIdx.x;
  __shared__ float rL0[512];
  __shared__ float rL1[512];
  rL0[o] = r32[(size_t)b0 * DM + o];
  rL1[o] = r32[(size_t)(b0 + 1) * DM + o];
  __syncthreads();
  float a0 = bo[o], a1 = a0;
  const float* wrow = Wo + (size_t)o * DM;
  for (int c = 0; c < DM; ++c) {
    float w = wrow[c];
    a0 += rL0[c] * w;
    a1 += rL1[c] * w;
  }
  dout[(size_t)b0 * DM + o]       = a0;
  dout[(size_t)(b0 + 1) * DM + o] = a1;
}

extern "C" void kernel_launch(void* const* d_in, const int* in_sizes, int n_in,
                              void* d_out, int out_size, void* d_ws, size_t ws_size,
                              hipStream_t stream) {
  // Defensive input identification by element count (deterministic).
  int ix = 0, iwih = 1, iwhh = 2, ibih = 3, ibhh = 4, iwo = 5, ibo = 6;
  {
    int b1 = -1, b2 = -1;
    for (int i = 0; i < n_in; ++i) {
      int s = in_sizes[i];
      if      (s == SEQ * BSZ * DM) ix = i;
      else if (s == 4608 * 1024)    iwih = i;
      else if (s == 4608 * 1536)    iwhh = i;
      else if (s == DM * DM)        iwo = i;
      else if (s == DM)             ibo = i;
      else if (s == 4608)           { if (b1 < 0) b1 = i; else b2 = i; }
    }
    if (b1 >= 0) ibih = b1;
    if (b2 >= 0) ibhh = b2;
  }
  const float* x   = (const float*)d_in[ix];
  const float* Wih = (const float*)d_in[iwih];
  const float* Whh = (const float*)d_in[iwhh];
  const float* bih = (const float*)d_in[ibih];
  const float* bhh = (const float*)d_in[ibhh];
  const float* Wo  = (const float*)d_in[iwo];
  const float* bo  = (const float*)d_in[ibo];

  char* ws = (char*)d_ws;
  unsigned short* Wh  = (unsigned short*)(ws + OFF_WBH);
  unsigned short* Wl  = (unsigned short*)(ws + OFF_WBL);
  float*          r32 = (float*)(ws + OFF_R32);
  unsigned*       bar = (unsigned*)(ws + OFF_BAR);
  float* dout = (float*)d_out;

  pk_wb  <<<11520, 256, 0, stream>>>(Wih, Whh, Wh, Wl, bar);
  pk_zero<<<4544,  256, 0, stream>>>((f32x4*)(ws + OFF_A));
  fused  <<<NBLK,  256, 0, stream>>>(x, bih, bhh, ws, dout);
  out_gemm<<<64, 512, 0, stream>>>(r32, Wo, bo, dout);
}

// Round 8
// 16033.003 us; speedup vs baseline: 5.2123x; 5.2123x over previous
//
#include <hip/hip_runtime.h>
#include <hip/hip_bf16.h>

// Problem constants
#define SEQ  256
#define BSZ  128
#define DM   512
#define HID  1536
#define KTOT 2560      // x(512) | r(512) | h(1536)
#define VC   6144      // virtual cols: [0,3072) fused rz, [3072,4608) inn, [4608,6144) hn
#define NBLK 720       // persistent grid = 45 groups x 16

typedef __attribute__((ext_vector_type(4))) float f32x4;
typedef __attribute__((ext_vector_type(8))) short short8;
typedef __attribute__((ext_vector_type(4))) unsigned short us4;
typedef __attribute__((ext_vector_type(8))) unsigned short us8;
typedef __attribute__((ext_vector_type(4))) unsigned int u32x4;

// ws layout (bytes)
#define OFF_WBH 0ull                 // bf16 [4608][2560] hi   = 23,592,960
#define OFF_WBL 23592960ull          // bf16 [4608][2560] lo   = 23,592,960
#define OFF_P   47185920ull          // f32  [5][128][6144]    = 15,728,640
#define OFF_R32 62914560ull          // f32  [128][512]        =    262,144
#define OFF_A   63176704ull          // f32  [1024][64][64]    = 16,777,216   (zeroed)
#define OFF_H32 79953920ull          // f32  [128][1536]       =    786,432   (zeroed)
#define OFF_RBH 80740352ull          // bf16 [128][512]  hi    (zeroed)
#define OFF_RBL 80871424ull          // bf16 [128][512]  lo    (zeroed)
#define OFF_HBH 81002496ull          // bf16 [128][1536] hi    (zeroed)
#define OFF_HBL 81395712ull          // bf16 [128][1536] lo    (zeroed)
#define OFF_BAR 81788928ull          // 1024 uints: root@0, ep@32, gcnt[g]@64+g*16
// pk_zero region: OFF_A..OFF_BAR = 18,612,224 B = 1,163,264 x 16B = 4544 blocks x 256

static __device__ __forceinline__ unsigned short bf(float x) {
  __hip_bfloat16 h = __float2bfloat16(x);
  return *reinterpret_cast<unsigned short*>(&h);
}
static __device__ __forceinline__ float bf2f(unsigned short u) {
  union { unsigned int i; float f; } c; c.i = ((unsigned int)u) << 16;
  return c.f;
}

// ---- cross-XCD coherence helpers: write THROUGH to LLC / read LLC-direct ----
static __device__ __forceinline__ void stf_llc(float* p, float v) {
  asm volatile("global_store_dword %0, %1, off sc0 sc1" :: "v"(p), "v"(v) : "memory");
}
static __device__ __forceinline__ void st16_llc(unsigned short* p, unsigned short v) {
  unsigned vv = v;
  asm volatile("global_store_short %0, %1, off sc0 sc1" :: "v"(p), "v"(vv) : "memory");
}
static __device__ __forceinline__ float ldf_llc(const float* p) {
  return __hip_atomic_load(p, __ATOMIC_RELAXED, __HIP_MEMORY_SCOPE_SYSTEM);
}
static __device__ __forceinline__ void ld2x16_llc(const unsigned short* p,
                                                  u32x4& r0, u32x4& r1) {
  asm volatile(
      "global_load_dwordx4 %0, %2, off sc0 sc1\n\t"
      "global_load_dwordx4 %1, %3, off sc0 sc1\n\t"
      "s_waitcnt vmcnt(0)"
      : "=&v"(r0), "=&v"(r1)
      : "v"(p), "v"(p + 8)
      : "memory");
}
static __device__ __forceinline__ unsigned sysld(unsigned* p) {
  return __hip_atomic_load(p, __ATOMIC_RELAXED, __HIP_MEMORY_SCOPE_SYSTEM);
}

// ---- grid barrier: hierarchical RMW arrive at LLC + SYSTEM poll. NO cache fences.
// Explicit vmcnt(0) drain per wave (inline-asm stores are invisible to the
// compiler's waitcnt bookkeeping) BEFORE the block barrier, so all write-through
// stores have reached the LLC before tid0 arrives.
static __device__ __forceinline__ void gsync(unsigned* bar) {
  asm volatile("s_waitcnt vmcnt(0)" ::: "memory");
  __syncthreads();
  if (threadIdx.x == 0) {
    unsigned* root = bar;
    unsigned* ep   = bar + 32;
    unsigned* gcnt = bar + 64 + (blockIdx.x >> 4) * 16;
    unsigned e = sysld(ep);
    if (atomicAdd(gcnt, 1u) == 15u) {
      atomicSub(gcnt, 16u);
      if (atomicAdd(root, 1u) == 44u) {
        atomicSub(root, 45u);
        atomicAdd(ep, 1u);
      }
    }
    while (sysld(ep) == e) __builtin_amdgcn_s_sleep(8);
  }
  __syncthreads();
}

// ---------------- prep: repack weights to hi/lo bf16 [4608][2560]; zero barrier ----------------
__global__ __launch_bounds__(256) void pk_wb(const float* __restrict__ Wih,
                                             const float* __restrict__ Whh,
                                             unsigned short* __restrict__ Wh,
                                             unsigned short* __restrict__ Wl,
                                             unsigned* __restrict__ bar) {
  if (blockIdx.x == 0)
    for (int i = threadIdx.x; i < 1024; i += 256) bar[i] = 0u;
  int idx = blockIdx.x * 256 + threadIdx.x;        // < 4608*640 = 2,949,120
  int row = idx / 640;
  int k = (idx - row * 640) * 4;
  const float* src = (k < 1024) ? (Wih + (size_t)row * 1024 + k)
                                : (Whh + (size_t)row * HID + (k - 1024));
  f32x4 v = *(const f32x4*)src;
  us4 oh, ol;
#pragma unroll
  for (int i = 0; i < 4; ++i) {
    unsigned short h = bf(v[i]);
    oh[i] = h;
    ol[i] = bf(v[i] - bf2f(h));
  }
  *(us4*)(Wh + (size_t)row * KTOT + k) = oh;
  *(us4*)(Wl + (size_t)row * KTOT + k) = ol;
}

__global__ __launch_bounds__(256) void pk_zero(f32x4* __restrict__ dst) {
  f32x4 z = {0.f, 0.f, 0.f, 0.f};
  dst[(size_t)blockIdx.x * 256 + threadIdx.x] = z;
}

// ---------------- persistent fused kernel: 256 x (GEMM | pair) ----------------
// 720 blocks x 256 threads. GEMM tasks: 720 = rz 96jg*5ks + inn 48jg*2ks + hn 48jg*3ks,
// each task = [128 b x 32 cols], K-chunk 512, hi/lo 3-term MFMA. W read once/step
// device-wide (plain cached loads, LLC-resident). Cross-XCD data: P and Rb/Hb via
// write-through sc0|sc1 stores + LLC-direct loads. XCD-private (h32, A): plain.
__global__ __launch_bounds__(256, 3) void fused(
    const float* __restrict__ x, const float* __restrict__ bih,
    const float* __restrict__ bhh, char* __restrict__ ws,
    float* __restrict__ dout)
{
  const unsigned short* Wh = (const unsigned short*)(ws + OFF_WBH);
  const unsigned short* Wl = (const unsigned short*)(ws + OFF_WBL);
  float*          P   = (float*)(ws + OFF_P);
  float*          r32 = (float*)(ws + OFF_R32);
  float*          A   = (float*)(ws + OFF_A);
  float*          h32 = (float*)(ws + OFF_H32);
  unsigned short* Rbh = (unsigned short*)(ws + OFF_RBH);
  unsigned short* Rbl = (unsigned short*)(ws + OFF_RBL);
  unsigned short* Hbh = (unsigned short*)(ws + OFF_HBH);
  unsigned short* Hbl = (unsigned short*)(ws + OFF_HBL);
  unsigned* bar = (unsigned*)(ws + OFF_BAR);

  const int blk = blockIdx.x;
  const int tid = threadIdx.x;

  // ---- static GEMM task decode (all 720 blocks valid) ----
  int jg, ks;
  if (blk < 480)      { jg = blk / 5;              ks = blk % 5; }
  else if (blk < 576) { int u = blk - 480; jg = 96  + u / 2; ks = u % 2; }
  else                { int u = blk - 576; jg = 144 + u / 3; ks = 2 + u % 3; }
  const int colb  = jg * 32;
  const int wrowb = (jg < 144 ? colb : colb - 1536);   // inn/hn share W rows [3072,4608)
  const int kc0   = ks * 512;

  const int wave = tid >> 6, lane = tid & 63;
  const int bh  = (wave & 1) * 64;        // b-half base
  const int jh  = (wave >> 1) * 16;       // col-16 base within the 32-col tile
  const int l15 = lane & 15, kg = lane >> 4;
  const int sr_ = tid >> 1;               // staging row 0..127
  const int sc_ = (tid & 1) * 16;         // staging col 0 or 16
  const int wrow0 = wrowb + jh;

  __shared__ __align__(16) unsigned short AH[128 * 40];
  __shared__ __align__(16) unsigned short AL[128 * 40];
  __shared__ __align__(16) float kS[4][64];
  __shared__ __align__(16) float qS[4][64];

  for (int t = 0; t < SEQ; ++t) {
    // ================= GEMM phase =================
    f32x4 acc[4];
#pragma unroll
    for (int i = 0; i < 4; ++i) acc[i] = (f32x4){0.f, 0.f, 0.f, 0.f};

    for (int it = 0; it < 16; ++it) {
      int kabs = kc0 + it * 32;
      us8 h0, h1, l0, l1;            // x path
      u32x4 a0, a1, b0, b1;          // r/h path (same bytes as us8)
      if (ks == 0) {                 // K [0,512): x (f32 -> hi/lo bf16)
        const float* p = x + ((size_t)t * BSZ + sr_) * DM + kabs + sc_;
        f32x4 f0 = ((const f32x4*)p)[0];
        f32x4 f1 = ((const f32x4*)p)[1];
        f32x4 f2 = ((const f32x4*)p)[2];
        f32x4 f3 = ((const f32x4*)p)[3];
#pragma unroll
        for (int i = 0; i < 4; ++i) {
          unsigned short hh = bf(f0[i]); h0[i]     = hh; l0[i]     = bf(f0[i] - bf2f(hh));
          hh = bf(f1[i]);                h0[4 + i] = hh; l0[4 + i] = bf(f1[i] - bf2f(hh));
          hh = bf(f2[i]);                h1[i]     = hh; l1[i]     = bf(f2[i] - bf2f(hh));
          hh = bf(f3[i]);                h1[4 + i] = hh; l1[4 + i] = bf(f3[i] - bf2f(hh));
        }
      } else if (ks == 1) {          // K [512,1024): r (bf16 hi/lo, LLC-fresh)
        size_t off = (size_t)sr_ * DM + (kabs - 512) + sc_;
        ld2x16_llc(Rbh + off, a0, a1);
        ld2x16_llc(Rbl + off, b0, b1);
      } else {                       // K [1024,2560): h (bf16 hi/lo, LLC-fresh)
        size_t off = (size_t)sr_ * HID + (kabs - 1024) + sc_;
        ld2x16_llc(Hbh + off, a0, a1);
        ld2x16_llc(Hbl + off, b0, b1);
      }
      __syncthreads();
      if (ks == 0) {
        *(us8*)&AH[sr_ * 40 + sc_]     = h0;
        *(us8*)&AH[sr_ * 40 + sc_ + 8] = h1;
        *(us8*)&AL[sr_ * 40 + sc_]     = l0;
        *(us8*)&AL[sr_ * 40 + sc_ + 8] = l1;
      } else {
        *(u32x4*)&AH[sr_ * 40 + sc_]     = a0;
        *(u32x4*)&AH[sr_ * 40 + sc_ + 8] = a1;
        *(u32x4*)&AL[sr_ * 40 + sc_]     = b0;
        *(u32x4*)&AL[sr_ * 40 + sc_ + 8] = b1;
      }
      __syncthreads();

      size_t woff = (size_t)(wrow0 + l15) * KTOT + kabs + kg * 8;
      short8 wh_ = *(const short8*)(Wh + woff);   // plain: W is read-only, LLC-resident
      short8 wl_ = *(const short8*)(Wl + woff);
#pragma unroll
      for (int bt = 0; bt < 4; ++bt) {
        short8 ah = *(const short8*)&AH[(bh + bt * 16 + l15) * 40 + kg * 8];
        short8 al = *(const short8*)&AL[(bh + bt * 16 + l15) * 40 + kg * 8];
        acc[bt] = __builtin_amdgcn_mfma_f32_16x16x32_bf16(ah, wh_, acc[bt], 0, 0, 0);
        acc[bt] = __builtin_amdgcn_mfma_f32_16x16x32_bf16(ah, wl_, acc[bt], 0, 0, 0);
        acc[bt] = __builtin_amdgcn_mfma_f32_16x16x32_bf16(al, wh_, acc[bt], 0, 0, 0);
      }
    }
    // P partials: write THROUGH to LLC (consumers may be on other XCDs)
#pragma unroll
    for (int bt = 0; bt < 4; ++bt)
#pragma unroll
      for (int i = 0; i < 4; ++i)
        stf_llc(&P[((size_t)ks * BSZ + bh + bt * 16 + kg * 4 + i) * VC + colb + jh + l15],
                acc[bt][i]);

    gsync(bar);

    // ================= pair phase (blocks 0..255, 4 pairs each) =================
    if (blk < 256) {
      int pw = tid >> 6;
      int pair = blk * 4 + pw;
      int b = pair >> 3, n = pair & 7;
      int l = lane;
      const float* Pb = P + (size_t)b * VC;
      float hv[3];
#pragma unroll
      for (int s = 0; s < 3; ++s) {
        int c = s * 512 + n * 64 + l;
        float sr2 = 0.f, sz = 0.f;
#pragma unroll
        for (int ksi = 0; ksi < 5; ++ksi) {
          const float* q = Pb + (size_t)ksi * BSZ * VC;
          sr2 += ldf_llc(q + c);
          sz  += ldf_llc(q + 1536 + c);
        }
        float gin = ldf_llc(Pb + 3072 + c) + ldf_llc(Pb + (size_t)BSZ * VC + 3072 + c);
        float ghn = 0.f;
#pragma unroll
        for (int ksi = 2; ksi < 5; ++ksi)
          ghn += ldf_llc(Pb + (size_t)ksi * BSZ * VC + 4608 + c);
        float rg = 1.f / (1.f + __expf(-(sr2 + bih[c] + bhh[c])));
        float zg = 1.f / (1.f + __expf(-(sz + bih[1536 + c] + bhh[1536 + c])));
        float nn = tanhf(gin + bih[3072 + c] + rg * (ghn + bhh[3072 + c]));
        size_t hix = (size_t)b * HID + c;
        float hp = h32[hix];                  // XCD-private (same block every step)
        float hnew = (1.f - zg) * nn + zg * hp;
        h32[hix] = hnew;
        unsigned short hh2 = bf(hnew);
        st16_llc(&Hbh[hix], hh2);             // cross-XCD: write through
        st16_llc(&Hbl[hix], bf(hnew - bf2f(hh2)));
        hv[s] = hnew;
      }
      float ssq = hv[0] * hv[0], ssk = hv[1] * hv[1];
#pragma unroll
      for (int off = 32; off > 0; off >>= 1) {
        ssq += __shfl_xor(ssq, off);
        ssk += __shfl_xor(ssk, off);
      }
      float qn = hv[0] * rsqrtf(ssq);
      float kn = hv[1] * rsqrtf(ssk);
      float ke = kn > 0.f ? kn : expm1f(kn);   // elu(unitnorm)
      kS[pw][l] = ke;
      qS[pw][l] = qn;                          // wave-local: no sync needed

      float vvl = hv[2];
      float* Arow = A + ((size_t)pair * 64 + l) * 64;   // XCD-private
      float racc = 0.f;
#pragma unroll
      for (int q4 = 0; q4 < 16; ++q4) {
        f32x4 a  = *(f32x4*)(Arow + q4 * 4);
        f32x4 kk = *(f32x4*)&kS[pw][q4 * 4];
        f32x4 qq = *(f32x4*)&qS[pw][q4 * 4];
        a[0] += kk[0] * vvl; a[1] += kk[1] * vvl;
        a[2] += kk[2] * vvl; a[3] += kk[3] * vvl;
        racc += qq[0] * a[0] + qq[1] * a[1] + qq[2] * a[2] + qq[3] * a[3];
        *(f32x4*)(Arow + q4 * 4) = a;
      }
      size_t ri = (size_t)b * DM + n * 64 + l;
      r32[ri] = racc;                          // read only after kernel end
      unsigned short rh2 = bf(racc);
      st16_llc(&Rbh[ri], rh2);                 // cross-XCD: write through
      st16_llc(&Rbl[ri], bf(racc - bf2f(rh2)));

      if (t == SEQ - 1) {
        dout[65536  + pair * 64 + l] = ke;     // k output (f32)
        dout[131072 + pair * 64 + l] = qn;     // q output (f32)
      }
    }
    gsync(bar);
  }
}

// ---------------- final: out = r @ Wo.T + bo (f32) ----------------
__global__ __launch_bounds__(512) void out_gemm(const float* __restrict__ r32,
                                                const float* __restrict__ Wo,
                                                const float* __restrict__ bo,
                                                float* __restrict__ dout) {
  int b0 = blockIdx.x * 2;
  int o  = threadIdx.x;
  __shared__ float rL0[512];
  __shared__ float rL1[512];
  rL0[o] = r32[(size_t)b0 * DM + o];
  rL1[o] = r32[(size_t)(b0 + 1) * DM + o];
  __syncthreads();
  float a0 = bo[o], a1 = a0;
  const float* wrow = Wo + (size_t)o * DM;
  for (int c = 0; c < DM; ++c) {
    float w = wrow[c];
    a0 += rL0[c] * w;
    a1 += rL1[c] * w;
  }
  dout[(size_t)b0 * DM + o]       = a0;
  dout[(size_t)(b0 + 1) * DM + o] = a1;
}

extern "C" void kernel_launch(void* const* d_in, const int* in_sizes, int n_in,
                              void* d_out, int out_size, void* d_ws, size_t ws_size,
                              hipStream_t stream) {
  // Defensive input identification by element count (deterministic).
  int ix = 0, iwih = 1, iwhh = 2, ibih = 3, ibhh = 4, iwo = 5, ibo = 6;
  {
    int b1 = -1, b2 = -1;
    for (int i = 0; i < n_in; ++i) {
      int s = in_sizes[i];
      if      (s == SEQ * BSZ * DM) ix = i;
      else if (s == 4608 * 1024)    iwih = i;
      else if (s == 4608 * 1536)    iwhh = i;
      else if (s == DM * DM)        iwo = i;
      else if (s == DM)             ibo = i;
      else if (s == 4608)           { if (b1 < 0) b1 = i; else b2 = i; }
    }
    if (b1 >= 0) ibih = b1;
    if (b2 >= 0) ibhh = b2;
  }
  const float* x   = (const float*)d_in[ix];
  const float* Wih = (const float*)d_in[iwih];
  const float* Whh = (const float*)d_in[iwhh];
  const float* bih = (const float*)d_in[ibih];
  const float* bhh = (const float*)d_in[ibhh];
  const float* Wo  = (const float*)d_in[iwo];
  const float* bo  = (const float*)d_in[ibo];

  char* ws = (char*)d_ws;
  unsigned short* Wh  = (unsigned short*)(ws + OFF_WBH);
  unsigned short* Wl  = (unsigned short*)(ws + OFF_WBL);
  float*          r32 = (float*)(ws + OFF_R32);
  unsigned*       bar = (unsigned*)(ws + OFF_BAR);
  float* dout = (float*)d_out;

  pk_wb  <<<11520, 256, 0, stream>>>(Wih, Whh, Wh, Wl, bar);
  pk_zero<<<4544,  256, 0, stream>>>((f32x4*)(ws + OFF_A));
  fused  <<<NBLK,  256, 0, stream>>>(x, bih, bhh, ws, dout);
  out_gemm<<<64, 512, 0, stream>>>(r32, Wo, bo, dout);
}

// Round 9
// 11433.875 us; speedup vs baseline: 7.3089x; 1.4022x over previous
//
#include <hip/hip_runtime.h>
#include <hip/hip_bf16.h>

// Problem constants
#define SEQ  256
#define BSZ  128
#define DM   512
#define HID  1536
#define KTOT 2560      // x(512) | r(512) | h(1536)
#define VC   6144      // virtual cols: [0,3072) fused rz, [3072,4608) inn, [4608,6144) hn
#define NBLK 720       // persistent grid = 45 groups x 16

typedef __attribute__((ext_vector_type(4))) float f32x4;
typedef __attribute__((ext_vector_type(8))) short short8;
typedef __attribute__((ext_vector_type(4))) unsigned short us4;
typedef __attribute__((ext_vector_type(8))) unsigned short us8;
typedef __attribute__((ext_vector_type(4))) unsigned int u32x4;

// ws layout (bytes)
#define OFF_WBH 0ull                 // bf16 [4608][2560] hi   = 23,592,960
#define OFF_WBL 23592960ull          // bf16 [4608][2560] lo   = 23,592,960
#define OFF_P   47185920ull          // f32  [5][128][6144]    = 15,728,640
#define OFF_R32 62914560ull          // f32  [128][512]  (written only at t=255)
#define OFF_RBH 80740352ull          // bf16 [128][512]  hi    (zeroed)
#define OFF_RBL 80871424ull          // bf16 [128][512]  lo    (zeroed)
#define OFF_HBH 81002496ull          // bf16 [128][1536] hi    (zeroed)
#define OFF_HBL 81395712ull          // bf16 [128][1536] lo    (zeroed)
#define OFF_BAR 81788928ull          // 1024 uints: root@0, ep@32, gcnt[g]@64+g*16
// pk_zero region: OFF_RBH..OFF_BAR = 1,048,576 B = 65,536 x 16B = 256 blocks x 256

static __device__ __forceinline__ unsigned short bf(float x) {
  __hip_bfloat16 h = __float2bfloat16(x);
  return *reinterpret_cast<unsigned short*>(&h);
}
static __device__ __forceinline__ float bf2f(unsigned short u) {
  union { unsigned int i; float f; } c; c.i = ((unsigned int)u) << 16;
  return c.f;
}

// ---- cross-XCD coherence helpers: write THROUGH to LLC / read LLC-direct ----
static __device__ __forceinline__ void stf_llc(float* p, float v) {
  asm volatile("global_store_dword %0, %1, off sc0 sc1" :: "v"(p), "v"(v) : "memory");
}
static __device__ __forceinline__ void st16_llc(unsigned short* p, unsigned short v) {
  unsigned vv = v;
  asm volatile("global_store_short %0, %1, off sc0 sc1" :: "v"(p), "v"(vv) : "memory");
}
static __device__ __forceinline__ float ldf_llc(const float* p) {
  return __hip_atomic_load(p, __ATOMIC_RELAXED, __HIP_MEMORY_SCOPE_SYSTEM);
}
static __device__ __forceinline__ void ld2p_llc(const unsigned short* p0,
                                                const unsigned short* p1,
                                                u32x4& r0, u32x4& r1) {
  asm volatile(
      "global_load_dwordx4 %0, %2, off sc0 sc1\n\t"
      "global_load_dwordx4 %1, %3, off sc0 sc1\n\t"
      "s_waitcnt vmcnt(0)"
      : "=&v"(r0), "=&v"(r1)
      : "v"(p0), "v"(p1)
      : "memory");
}
static __device__ __forceinline__ unsigned sysld(unsigned* p) {
  return __hip_atomic_load(p, __ATOMIC_RELAXED, __HIP_MEMORY_SCOPE_SYSTEM);
}

// ---- grid barrier: hierarchical RMW arrive at LLC + SYSTEM poll. NO cache fences.
static __device__ __forceinline__ void gsync(unsigned* bar) {
  asm volatile("s_waitcnt vmcnt(0)" ::: "memory");   // drain inline-asm stores
  __syncthreads();
  if (threadIdx.x == 0) {
    unsigned* root = bar;
    unsigned* ep   = bar + 32;
    unsigned* gcnt = bar + 64 + (blockIdx.x >> 4) * 16;
    unsigned e = sysld(ep);
    if (atomicAdd(gcnt, 1u) == 15u) {
      atomicSub(gcnt, 16u);
      if (atomicAdd(root, 1u) == 44u) {
        atomicSub(root, 45u);
        atomicAdd(ep, 1u);
      }
    }
    while (sysld(ep) == e) __builtin_amdgcn_s_sleep(8);
  }
  __syncthreads();
}

// ---------------- prep: repack weights to hi/lo bf16 [4608][2560]; zero barrier ----------------
__global__ __launch_bounds__(256) void pk_wb(const float* __restrict__ Wih,
                                             const float* __restrict__ Whh,
                                             unsigned short* __restrict__ Wh,
                                             unsigned short* __restrict__ Wl,
                                             unsigned* __restrict__ bar) {
  if (blockIdx.x == 0)
    for (int i = threadIdx.x; i < 1024; i += 256) bar[i] = 0u;
  int idx = blockIdx.x * 256 + threadIdx.x;        // < 4608*640 = 2,949,120
  int row = idx / 640;
  int k = (idx - row * 640) * 4;
  const float* src = (k < 1024) ? (Wih + (size_t)row * 1024 + k)
                                : (Whh + (size_t)row * HID + (k - 1024));
  f32x4 v = *(const f32x4*)src;
  us4 oh, ol;
#pragma unroll
  for (int i = 0; i < 4; ++i) {
    unsigned short h = bf(v[i]);
    oh[i] = h;
    ol[i] = bf(v[i] - bf2f(h));
  }
  *(us4*)(Wh + (size_t)row * KTOT + k) = oh;
  *(us4*)(Wl + (size_t)row * KTOT + k) = ol;
}

__global__ __launch_bounds__(256) void pk_zero(f32x4* __restrict__ dst) {
  f32x4 z = {0.f, 0.f, 0.f, 0.f};
  dst[(size_t)blockIdx.x * 256 + threadIdx.x] = z;
}

// ---------------- persistent fused kernel: 256 x (GEMM | pair) ----------------
// 720 blocks x 256 threads. Tile [64b x 64j x 512k]: 720 = 2 bhalf x
// (rz 48jg*5ks + inn 24jg*2ks + hn 24jg*3ks). W plain-cached (LLC-resident).
// Cross-XCD: P & Rb/Hb write-through sc0|sc1, LLC-direct reads. A in LDS
// (512 pair-blocks x 2 pairs, stride-65 pad). h state in registers.
__global__ __launch_bounds__(256, 3) void fused(
    const float* __restrict__ x, const float* __restrict__ bih,
    const float* __restrict__ bhh, char* __restrict__ ws,
    float* __restrict__ dout)
{
  const unsigned short* Wh = (const unsigned short*)(ws + OFF_WBH);
  const unsigned short* Wl = (const unsigned short*)(ws + OFF_WBL);
  float*          P   = (float*)(ws + OFF_P);
  float*          r32 = (float*)(ws + OFF_R32);
  unsigned short* Rbh = (unsigned short*)(ws + OFF_RBH);
  unsigned short* Rbl = (unsigned short*)(ws + OFF_RBL);
  unsigned short* Hbh = (unsigned short*)(ws + OFF_HBH);
  unsigned short* Hbl = (unsigned short*)(ws + OFF_HBL);
  unsigned* bar = (unsigned*)(ws + OFF_BAR);

  const int blk = blockIdx.x;
  const int tid = threadIdx.x;

  // ---- static GEMM task decode ----
  const int half = blk & 1;
  const int u = blk >> 1;                 // 0..359
  int jg, ks;
  if (u < 240)      { jg = u / 5;              ks = u % 5; }
  else if (u < 288) { int v = u - 240; jg = 48 + v / 2; ks = v % 2; }
  else              { int v = u - 288; jg = 72 + v / 3; ks = 2 + v % 3; }
  int colb, wrowb;
  if (jg < 48)      { colb = jg * 64;               wrowb = colb; }          // rz
  else if (jg < 72) { colb = 3072 + (jg - 48) * 64; wrowb = colb; }          // inn
  else              { colb = 4608 + (jg - 72) * 64; wrowb = colb - 1536; }   // hn
  const int kc0 = ks * 512;
  const int b0g = half * 64;              // global batch base of this tile

  const int wave = tid >> 6, lane = tid & 63;
  const int jh  = wave * 16;              // wave's 16-col slice of the 64-col tile
  const int l15 = lane & 15, kg = lane >> 4;
  const int sr_ = tid >> 2;               // staging row 0..63
  const int sc_ = (tid & 3) * 8;          // staging col (8 shorts per thread)
  const int wrow0 = wrowb + jh;

  __shared__ __align__(16) unsigned short AH[64 * 40];
  __shared__ __align__(16) unsigned short AL[64 * 40];
  __shared__ __align__(16) float Alds[2][64 * 65];   // per-pair fast weights
  __shared__ float kS[2][64];
  __shared__ float qS[2][64];

  // ---- init: zero A (LDS) ----
  for (int i = tid; i < 2 * 64 * 65; i += 256) ((float*)Alds)[i] = 0.f;
  float hprev[3] = {0.f, 0.f, 0.f};       // per-pair-lane GRU state (waves 0,1 of blk<512)
  gsync(bar);

  for (int t = 0; t < SEQ; ++t) {
    // ================= GEMM phase =================
    f32x4 acc[4];
#pragma unroll
    for (int i = 0; i < 4; ++i) acc[i] = (f32x4){0.f, 0.f, 0.f, 0.f};

    for (int it = 0; it < 16; ++it) {
      int kabs = kc0 + it * 32;
      us8 h0, l0;                     // x path
      u32x4 a0, b0;                   // r/h path (same bytes)
      if (ks == 0) {                  // K [0,512): x (f32 -> hi/lo bf16)
        const float* p = x + ((size_t)(t * BSZ + b0g + sr_)) * DM + kabs + sc_;
        f32x4 f0 = ((const f32x4*)p)[0];
        f32x4 f1 = ((const f32x4*)p)[1];
#pragma unroll
        for (int i = 0; i < 4; ++i) {
          unsigned short hh = bf(f0[i]); h0[i]     = hh; l0[i]     = bf(f0[i] - bf2f(hh));
          hh = bf(f1[i]);                h0[4 + i] = hh; l0[4 + i] = bf(f1[i] - bf2f(hh));
        }
      } else if (ks == 1) {           // K [512,1024): r (bf16 hi/lo, LLC-fresh)
        size_t off = (size_t)(b0g + sr_) * DM + (kabs - 512) + sc_;
        ld2p_llc(Rbh + off, Rbl + off, a0, b0);
      } else {                        // K [1024,2560): h (bf16 hi/lo, LLC-fresh)
        size_t off = (size_t)(b0g + sr_) * HID + (kabs - 1024) + sc_;
        ld2p_llc(Hbh + off, Hbl + off, a0, b0);
      }
      __syncthreads();
      if (ks == 0) {
        *(us8*)&AH[sr_ * 40 + sc_] = h0;
        *(us8*)&AL[sr_ * 40 + sc_] = l0;
      } else {
        *(u32x4*)&AH[sr_ * 40 + sc_] = a0;
        *(u32x4*)&AL[sr_ * 40 + sc_] = b0;
      }
      __syncthreads();

      size_t woff = (size_t)(wrow0 + l15) * KTOT + kabs + kg * 8;
      short8 wh_ = *(const short8*)(Wh + woff);   // plain: read-only, LLC-resident
      short8 wl_ = *(const short8*)(Wl + woff);
#pragma unroll
      for (int bt = 0; bt < 4; ++bt) {
        short8 ah = *(const short8*)&AH[(bt * 16 + l15) * 40 + kg * 8];
        short8 al = *(const short8*)&AL[(bt * 16 + l15) * 40 + kg * 8];
        acc[bt] = __builtin_amdgcn_mfma_f32_16x16x32_bf16(ah, wh_, acc[bt], 0, 0, 0);
        acc[bt] = __builtin_amdgcn_mfma_f32_16x16x32_bf16(ah, wl_, acc[bt], 0, 0, 0);
        acc[bt] = __builtin_amdgcn_mfma_f32_16x16x32_bf16(al, wh_, acc[bt], 0, 0, 0);
      }
    }
    // P partials: write THROUGH to LLC (cross-XCD consumers)
#pragma unroll
    for (int bt = 0; bt < 4; ++bt)
#pragma unroll
      for (int i = 0; i < 4; ++i)
        stf_llc(&P[((size_t)ks * BSZ + b0g + bt * 16 + kg * 4 + i) * VC + colb + jh + l15],
                acc[bt][i]);

    gsync(bar);

    // ================= pair phase (blocks 0..511, waves 0..1, 1 pair each) ==========
    if (blk < 512 && wave < 2) {
      const int pair = blk * 2 + wave;
      const int b = pair >> 3, n = pair & 7;
      const int l = lane;
      const float* Pb = P + (size_t)b * VC;
      float hv[3];
#pragma unroll
      for (int s = 0; s < 3; ++s) {
        int c = s * 512 + n * 64 + l;
        float sr2 = 0.f, sz = 0.f;
#pragma unroll
        for (int ksi = 0; ksi < 5; ++ksi) {
          const float* q = Pb + (size_t)ksi * BSZ * VC;
          sr2 += ldf_llc(q + c);
          sz  += ldf_llc(q + 1536 + c);
        }
        float gin = ldf_llc(Pb + 3072 + c) + ldf_llc(Pb + (size_t)BSZ * VC + 3072 + c);
        float ghn = 0.f;
#pragma unroll
        for (int ksi = 2; ksi < 5; ++ksi)
          ghn += ldf_llc(Pb + (size_t)ksi * BSZ * VC + 4608 + c);
        float rg = 1.f / (1.f + __expf(-(sr2 + bih[c] + bhh[c])));
        float zg = 1.f / (1.f + __expf(-(sz + bih[1536 + c] + bhh[1536 + c])));
        float nn = tanhf(gin + bih[3072 + c] + rg * (ghn + bhh[3072 + c]));
        float hnew = (1.f - zg) * nn + zg * hprev[s];
        hprev[s] = hnew;
        size_t hix = (size_t)b * HID + c;
        unsigned short hh2 = bf(hnew);
        st16_llc(&Hbh[hix], hh2);
        st16_llc(&Hbl[hix], bf(hnew - bf2f(hh2)));
        hv[s] = hnew;
      }
      float ssq = hv[0] * hv[0], ssk = hv[1] * hv[1];
#pragma unroll
      for (int off = 32; off > 0; off >>= 1) {
        ssq += __shfl_xor(ssq, off);
        ssk += __shfl_xor(ssk, off);
      }
      float qn = hv[0] * rsqrtf(ssq);
      float kn = hv[1] * rsqrtf(ssk);
      float ke = kn > 0.f ? kn : expm1f(kn);   // elu(unitnorm)
      kS[wave][l] = ke;
      qS[wave][l] = qn;                        // wave-local LDS: lockstep, no block sync

      float vvl = hv[2];
      float* Arow = &Alds[wave][l * 65];       // stride 65: 2 lanes/bank = conflict-free
      float racc = 0.f;
#pragma unroll
      for (int q4 = 0; q4 < 16; ++q4) {
        float a0 = Arow[q4 * 4 + 0], a1 = Arow[q4 * 4 + 1];
        float a2 = Arow[q4 * 4 + 2], a3 = Arow[q4 * 4 + 3];
        float k0 = kS[wave][q4 * 4 + 0], k1 = kS[wave][q4 * 4 + 1];
        float k2 = kS[wave][q4 * 4 + 2], k3 = kS[wave][q4 * 4 + 3];
        float q0 = qS[wave][q4 * 4 + 0], q1 = qS[wave][q4 * 4 + 1];
        float q2 = qS[wave][q4 * 4 + 2], q3 = qS[wave][q4 * 4 + 3];
        a0 += k0 * vvl; a1 += k1 * vvl; a2 += k2 * vvl; a3 += k3 * vvl;
        racc += q0 * a0 + q1 * a1 + q2 * a2 + q3 * a3;
        Arow[q4 * 4 + 0] = a0; Arow[q4 * 4 + 1] = a1;
        Arow[q4 * 4 + 2] = a2; Arow[q4 * 4 + 3] = a3;
      }
      size_t ri = (size_t)b * DM + n * 64 + l;
      unsigned short rh2 = bf(racc);
      st16_llc(&Rbh[ri], rh2);
      st16_llc(&Rbl[ri], bf(racc - bf2f(rh2)));

      if (t == SEQ - 1) {
        r32[ri] = racc;                        // final r (plain; kernel-end flush)
        dout[65536  + pair * 64 + l] = ke;     // k output (f32)
        dout[131072 + pair * 64 + l] = qn;     // q output (f32)
      }
    }
    gsync(bar);
  }
}

// ---------------- final: out = r @ Wo.T + bo (f32) ----------------
__global__ __launch_bounds__(512) void out_gemm(const float* __restrict__ r32,
                                                const float* __restrict__ Wo,
                                                const float* __restrict__ bo,
                                                float* __restrict__ dout) {
  int b0 = blockIdx.x * 2;
  int o  = threadIdx.x;
  __shared__ float rL0[512];
  __shared__ float rL1[512];
  rL0[o] = r32[(size_t)b0 * DM + o];
  rL1[o] = r32[(size_t)(b0 + 1) * DM + o];
  __syncthreads();
  float a0 = bo[o], a1 = a0;
  const float* wrow = Wo + (size_t)o * DM;
  for (int c = 0; c < DM; ++c) {
    float w = wrow[c];
    a0 += rL0[c] * w;
    a1 += rL1[c] * w;
  }
  dout[(size_t)b0 * DM + o]       = a0;
  dout[(size_t)(b0 + 1) * DM + o] = a1;
}

extern "C" void kernel_launch(void* const* d_in, const int* in_sizes, int n_in,
                              void* d_out, int out_size, void* d_ws, size_t ws_size,
                              hipStream_t stream) {
  // Defensive input identification by element count (deterministic).
  int ix = 0, iwih = 1, iwhh = 2, ibih = 3, ibhh = 4, iwo = 5, ibo = 6;
  {
    int b1 = -1, b2 = -1;
    for (int i = 0; i < n_in; ++i) {
      int s = in_sizes[i];
      if      (s == SEQ * BSZ * DM) ix = i;
      else if (s == 4608 * 1024)    iwih = i;
      else if (s == 4608 * 1536)    iwhh = i;
      else if (s == DM * DM)        iwo = i;
      else if (s == DM)             ibo = i;
      else if (s == 4608)           { if (b1 < 0) b1 = i; else b2 = i; }
    }
    if (b1 >= 0) ibih = b1;
    if (b2 >= 0) ibhh = b2;
  }
  const float* x   = (const float*)d_in[ix];
  const float* Wih = (const float*)d_in[iwih];
  const float* Whh = (const float*)d_in[iwhh];
  const float* bih = (const float*)d_in[ibih];
  const float* bhh = (const float*)d_in[ibhh];
  const float* Wo  = (const float*)d_in[iwo];
  const float* bo  = (const float*)d_in[ibo];

  char* ws = (char*)d_ws;
  unsigned short* Wh  = (unsigned short*)(ws + OFF_WBH);
  unsigned short* Wl  = (unsigned short*)(ws + OFF_WBL);
  float*          r32 = (float*)(ws + OFF_R32);
  unsigned*       bar = (unsigned*)(ws + OFF_BAR);
  float* dout = (float*)d_out;

  pk_wb  <<<11520, 256, 0, stream>>>(Wih, Whh, Wh, Wl, bar);
  pk_zero<<<256,   256, 0, stream>>>((f32x4*)(ws + OFF_RBH));
  fused  <<<NBLK,  256, 0, stream>>>(x, bih, bhh, ws, dout);
  out_gemm<<<64, 512, 0, stream>>>(r32, Wo, bo, dout);
}